// Round 1
// baseline (864.001 us; speedup 1.0000x reference)
//
#include <hip/hip_runtime.h>
#include <hip/hip_bf16.h>

// Problem constants (fixed by the reference)
#define N_INST 262144
#define E_DIM  512
#define H_DIM  256
#define NBAGS  512
#define MI     64          // instances per block
#define XS_STRIDE 520      // bf16 elems per LDS row (+8 pad breaks bank aliasing)

typedef __bf16 bf16x8 __attribute__((ext_vector_type(8)));
typedef float  f32x4  __attribute__((ext_vector_type(4)));

// ---- prep: convert Vw fp32 -> bf16 (256x512, reused by all 4096 blocks via L2)
__global__ void vw_to_bf16(const float* __restrict__ src,
                           __hip_bfloat16* __restrict__ dst) {
    int i = (blockIdx.x * 256 + threadIdx.x) * 4;
    float4 f = *(const float4*)(src + i);
    dst[i + 0] = __float2bfloat16(f.x);
    dst[i + 1] = __float2bfloat16(f.y);
    dst[i + 2] = __float2bfloat16(f.z);
    dst[i + 3] = __float2bfloat16(f.w);
}

// ---- main fused kernel: GEMM(tanh) -> ww-dot -> exp -> segmented weighted acc
__global__ __launch_bounds__(256, 2) void attn_main(
    const float* __restrict__ X,             // [N, E] fp32
    const __hip_bfloat16* __restrict__ Vw,   // [H, E] bf16
    const float* __restrict__ Vb,            // [H]
    const float* __restrict__ ww,            // [H]
    const float* __restrict__ wb,            // [1]
    const int* __restrict__ bidx,            // [N] sorted
    float* __restrict__ bag_acc,             // [NBAGS, E] fp32 (zeroed)
    float* __restrict__ sum_alphas)          // [NBAGS] fp32 (zeroed)
{
    __shared__ __hip_bfloat16 xs[MI][XS_STRIDE];  // 66560 B
    __shared__ float s_part[4][MI];
    __shared__ float a_sh[MI];
    __shared__ int   bag_sh[MI];

    const int tid = threadIdx.x;
    const int i0  = blockIdx.x * MI;

    if (tid < MI) bag_sh[tid] = bidx[i0 + tid];

    // ---- stage 1: X tile [64][512] fp32 -> bf16 LDS, coalesced float4 loads
    {
        const int c4 = tid & 127;   // float4 column 0..127
        const int r2 = tid >> 7;    // 0..1
        for (int rr = 0; rr < MI; rr += 2) {
            const int r = rr + r2;
            float4 f = *(const float4*)(X + (size_t)(i0 + r) * E_DIM + c4 * 4);
            __hip_bfloat16* dst = &xs[r][c4 * 4];
            dst[0] = __float2bfloat16(f.x);
            dst[1] = __float2bfloat16(f.y);
            dst[2] = __float2bfloat16(f.z);
            dst[3] = __float2bfloat16(f.w);
        }
    }
    __syncthreads();

    // ---- stage 2: GEMM. wave w computes rows 0..63 x cols [w*64, w*64+64)
    const int wave = tid >> 6;
    const int lane = tid & 63;
    const int l16  = lane & 15;
    const int kgrp = lane >> 4;     // 0..3

    f32x4 acc[4][4];                // [mt][nt]
    for (int mt = 0; mt < 4; mt++)
        for (int nt = 0; nt < 4; nt++)
            acc[mt][nt] = (f32x4){0.f, 0.f, 0.f, 0.f};

    for (int k0 = 0; k0 < E_DIM; k0 += 32) {
        bf16x8 a_frag[4], b_frag[4];
        const int kc = k0 + kgrp * 8;
        for (int mt = 0; mt < 4; mt++)
            a_frag[mt] = *(const bf16x8*)&xs[mt * 16 + l16][kc];
        for (int nt = 0; nt < 4; nt++) {
            const int h = wave * 64 + nt * 16 + l16;
            b_frag[nt] = *(const bf16x8*)((const __bf16*)Vw + (size_t)h * E_DIM + kc);
        }
        for (int mt = 0; mt < 4; mt++)
            for (int nt = 0; nt < 4; nt++)
                acc[mt][nt] = __builtin_amdgcn_mfma_f32_16x16x32_bf16(
                    a_frag[mt], b_frag[nt], acc[mt][nt], 0, 0, 0);
    }

    // ---- stage 3: epilogue. v = tanh(acc + Vb); s_partial = sum_h ww[h]*v
    float ww_r[4], vb_r[4];
    for (int nt = 0; nt < 4; nt++) {
        const int h = wave * 64 + nt * 16 + l16;
        ww_r[nt] = ww[h];
        vb_r[nt] = Vb[h];
    }
    for (int mt = 0; mt < 4; mt++) {
        for (int r = 0; r < 4; r++) {
            float t = 0.f;
            for (int nt = 0; nt < 4; nt++) {
                float v = tanhf(acc[mt][nt][r] + vb_r[nt]);
                t += ww_r[nt] * v;
            }
            // reduce across the 16 lanes (l16) sharing this instance
            for (int off = 1; off < 16; off <<= 1)
                t += __shfl_xor(t, off, 64);
            if (l16 == 0)
                s_part[wave][mt * 16 + kgrp * 4 + r] = t;
        }
    }
    __syncthreads();

    if (tid < MI) {
        float s = s_part[0][tid] + s_part[1][tid] + s_part[2][tid] +
                  s_part[3][tid] + wb[0];
        a_sh[tid] = expf(s);
    }
    __syncthreads();

    // ---- stage 4: segmented weighted accumulation (bidx is sorted)
    {
        const int e0 = tid * 2;
        float c0 = 0.f, c1 = 0.f, asum = 0.f;
        for (int i = 0; i < MI; i++) {
            const float a = a_sh[i];
            __hip_bfloat162 p = *(const __hip_bfloat162*)&xs[i][e0];
            c0 += a * __low2float(p);
            c1 += a * __high2float(p);
            asum += a;
            const bool flush = (i == MI - 1) || (bag_sh[i + 1] != bag_sh[i]);
            if (flush) {
                const int b = bag_sh[i];
                atomicAdd(&bag_acc[(size_t)b * E_DIM + e0], c0);
                atomicAdd(&bag_acc[(size_t)b * E_DIM + e0 + 1], c1);
                if (tid == 0) atomicAdd(&sum_alphas[b], asum);
                c0 = 0.f; c1 = 0.f; asum = 0.f;
            }
        }
    }
}

// ---- finalize: bag_sum = acc/sum, logits = bag_sum . dw^T + db, softmax
__global__ void finalize(const float* __restrict__ bag_acc,
                         const float* __restrict__ sum_alphas,
                         const float* __restrict__ dw,
                         const float* __restrict__ db,
                         float* __restrict__ out) {
    const int b = blockIdx.x;
    const int lane = threadIdx.x;
    const float sa = sum_alphas[b];
    const float inv = (sa > 0.f) ? (1.f / sa) : 0.f;   // empty bag -> bag_sum 0
    float l0 = 0.f, l1 = 0.f;
    for (int e = lane; e < E_DIM; e += 64) {
        const float bs = bag_acc[(size_t)b * E_DIM + e] * inv;
        l0 += bs * dw[e];
        l1 += bs * dw[E_DIM + e];
    }
    for (int off = 32; off; off >>= 1) {
        l0 += __shfl_xor(l0, off, 64);
        l1 += __shfl_xor(l1, off, 64);
    }
    if (lane == 0) {
        l0 += db[0];
        l1 += db[1];
        const float m  = fmaxf(l0, l1);
        const float e0 = expf(l0 - m), e1 = expf(l1 - m);
        const float is = 1.f / (e0 + e1);
        out[b * 2 + 0] = e0 * is;
        out[b * 2 + 1] = e1 * is;
    }
}

extern "C" void kernel_launch(void* const* d_in, const int* in_sizes, int n_in,
                              void* d_out, int out_size, void* d_ws, size_t ws_size,
                              hipStream_t stream) {
    const float* X   = (const float*)d_in[0];  // bag_encoding [N,E]
    const float* Vwf = (const float*)d_in[1];  // [H,E]
    const float* Vb  = (const float*)d_in[2];  // [H]
    const float* ww  = (const float*)d_in[3];  // [1,H]
    const float* wb  = (const float*)d_in[4];  // [1]
    const float* dw  = (const float*)d_in[5];  // [2,E]
    const float* db  = (const float*)d_in[6];  // [2]
    const int*  bidx = (const int*)d_in[7];    // [N]
    float* out = (float*)d_out;

    // workspace layout: [Vw bf16: 256 KB][bag_acc: 1 MB][sum_alphas: 2 KB]
    __hip_bfloat16* Vwb = (__hip_bfloat16*)d_ws;
    float* bag_acc    = (float*)((char*)d_ws + (size_t)H_DIM * E_DIM * 2);
    float* sum_alphas = bag_acc + (size_t)NBAGS * E_DIM;

    hipMemsetAsync(bag_acc, 0, ((size_t)NBAGS * E_DIM + NBAGS) * sizeof(float), stream);
    vw_to_bf16<<<H_DIM * E_DIM / 1024, 256, 0, stream>>>(Vwf, Vwb);
    attn_main<<<N_INST / MI, 256, 0, stream>>>(X, Vwb, Vb, ww, wb, bidx,
                                               bag_acc, sum_alphas);
    finalize<<<NBAGS, 64, 0, stream>>>(bag_acc, sum_alphas, dw, db, out);
}

// Round 2
// 860.115 us; speedup vs baseline: 1.0045x; 1.0045x over previous
//
#include <hip/hip_runtime.h>
#include <hip/hip_bf16.h>

// Problem constants (fixed by the reference)
#define N_INST 262144
#define E_DIM  512
#define H_DIM  256
#define NBAGS  512
#define MI     32          // instances per block (32 -> 34 KB LDS -> 4 blocks/CU)
#define XS_STRIDE 520      // bf16 elems per LDS row (+8 pad: row offset = 4 banks, 2-way on b128 reads = free)

typedef __bf16 bf16x8 __attribute__((ext_vector_type(8)));
typedef float  f32x4  __attribute__((ext_vector_type(4)));

// ---- prep: convert Vw fp32 -> bf16 (256x512, reused by all blocks via L2)
__global__ void vw_to_bf16(const float* __restrict__ src,
                           __hip_bfloat16* __restrict__ dst) {
    int i = (blockIdx.x * 256 + threadIdx.x) * 4;
    float4 f = *(const float4*)(src + i);
    dst[i + 0] = __float2bfloat16(f.x);
    dst[i + 1] = __float2bfloat16(f.y);
    dst[i + 2] = __float2bfloat16(f.z);
    dst[i + 3] = __float2bfloat16(f.w);
}

// ---- main fused kernel: GEMM(tanh) -> ww-dot -> exp -> segmented weighted acc
__global__ __launch_bounds__(256, 4) void attn_main(
    const float* __restrict__ X,             // [N, E] fp32
    const __hip_bfloat16* __restrict__ Vw,   // [H, E] bf16
    const float* __restrict__ Vb,            // [H]
    const float* __restrict__ ww,            // [H]
    const float* __restrict__ wb,            // [1]
    const int* __restrict__ bidx,            // [N] sorted
    float* __restrict__ bag_acc,             // [NBAGS, E] fp32 (zeroed)
    float* __restrict__ sum_alphas)          // [NBAGS] fp32 (zeroed)
{
    __shared__ __hip_bfloat16 xs[MI][XS_STRIDE];  // 33280 B
    __shared__ float s_part[4][MI];
    __shared__ float a_sh[MI];
    __shared__ int   bag_sh[MI];

    const int tid = threadIdx.x;
    const int i0  = blockIdx.x * MI;

    if (tid < MI) bag_sh[tid] = bidx[i0 + tid];

    // ---- stage 1: X tile [32][512] fp32 -> bf16 LDS, coalesced float4 loads
    {
        const int c4 = tid & 127;   // float4 column 0..127
        const int r2 = tid >> 7;    // 0..1
        for (int rr = 0; rr < MI; rr += 2) {
            const int r = rr + r2;
            float4 f = *(const float4*)(X + (size_t)(i0 + r) * E_DIM + c4 * 4);
            __hip_bfloat16* dst = &xs[r][c4 * 4];
            dst[0] = __float2bfloat16(f.x);
            dst[1] = __float2bfloat16(f.y);
            dst[2] = __float2bfloat16(f.z);
            dst[3] = __float2bfloat16(f.w);
        }
    }
    __syncthreads();

    // ---- stage 2: GEMM. wave w computes rows 0..31 x cols [w*64, w*64+64)
    const int wave = tid >> 6;
    const int lane = tid & 63;
    const int l16  = lane & 15;
    const int kgrp = lane >> 4;     // 0..3

    f32x4 acc[2][4];                // [mt][nt]
    for (int mt = 0; mt < 2; mt++)
        for (int nt = 0; nt < 4; nt++)
            acc[mt][nt] = (f32x4){0.f, 0.f, 0.f, 0.f};

    for (int k0 = 0; k0 < E_DIM; k0 += 32) {
        bf16x8 a_frag[2], b_frag[4];
        const int kc = k0 + kgrp * 8;
        for (int nt = 0; nt < 4; nt++) {
            const int h = wave * 64 + nt * 16 + l16;
            b_frag[nt] = *(const bf16x8*)((const __bf16*)Vw + (size_t)h * E_DIM + kc);
        }
        for (int mt = 0; mt < 2; mt++)
            a_frag[mt] = *(const bf16x8*)&xs[mt * 16 + l16][kc];
        for (int mt = 0; mt < 2; mt++)
            for (int nt = 0; nt < 4; nt++)
                acc[mt][nt] = __builtin_amdgcn_mfma_f32_16x16x32_bf16(
                    a_frag[mt], b_frag[nt], acc[mt][nt], 0, 0, 0);
    }

    // ---- stage 3: epilogue. v = tanh(acc + Vb); s_partial = sum_h ww[h]*v
    float ww_r[4], vb_r[4];
    for (int nt = 0; nt < 4; nt++) {
        const int h = wave * 64 + nt * 16 + l16;
        ww_r[nt] = ww[h];
        vb_r[nt] = Vb[h];
    }
    for (int mt = 0; mt < 2; mt++) {
        for (int r = 0; r < 4; r++) {
            float t = 0.f;
            for (int nt = 0; nt < 4; nt++) {
                float v = tanhf(acc[mt][nt][r] + vb_r[nt]);
                t += ww_r[nt] * v;
            }
            // reduce across the 16 lanes (l16) sharing this instance
            for (int off = 1; off < 16; off <<= 1)
                t += __shfl_xor(t, off, 64);
            if (l16 == 0)
                s_part[wave][mt * 16 + kgrp * 4 + r] = t;
        }
    }
    __syncthreads();

    if (tid < MI) {
        float s = s_part[0][tid] + s_part[1][tid] + s_part[2][tid] +
                  s_part[3][tid] + wb[0];
        a_sh[tid] = expf(s);
    }
    __syncthreads();

    // ---- stage 4: segmented weighted accumulation (bidx is sorted)
    {
        const int e0 = tid * 2;
        float c0 = 0.f, c1 = 0.f, asum = 0.f;
        for (int i = 0; i < MI; i++) {
            const float a = a_sh[i];
            __hip_bfloat162 p = *(const __hip_bfloat162*)&xs[i][e0];
            c0 += a * __low2float(p);
            c1 += a * __high2float(p);
            asum += a;
            const bool flush = (i == MI - 1) || (bag_sh[i + 1] != bag_sh[i]);
            if (flush) {
                const int b = bag_sh[i];
                atomicAdd(&bag_acc[(size_t)b * E_DIM + e0], c0);
                atomicAdd(&bag_acc[(size_t)b * E_DIM + e0 + 1], c1);
                if (tid == 0) atomicAdd(&sum_alphas[b], asum);
                c0 = 0.f; c1 = 0.f; asum = 0.f;
            }
        }
    }
}

// ---- finalize: bag_sum = acc/sum, logits = bag_sum . dw^T + db, softmax
__global__ void finalize(const float* __restrict__ bag_acc,
                         const float* __restrict__ sum_alphas,
                         const float* __restrict__ dw,
                         const float* __restrict__ db,
                         float* __restrict__ out) {
    const int b = blockIdx.x;
    const int lane = threadIdx.x;
    const float sa = sum_alphas[b];
    const float inv = (sa > 0.f) ? (1.f / sa) : 0.f;   // empty bag -> bag_sum 0
    float l0 = 0.f, l1 = 0.f;
    for (int e = lane; e < E_DIM; e += 64) {
        const float bs = bag_acc[(size_t)b * E_DIM + e] * inv;
        l0 += bs * dw[e];
        l1 += bs * dw[E_DIM + e];
    }
    for (int off = 32; off; off >>= 1) {
        l0 += __shfl_xor(l0, off, 64);
        l1 += __shfl_xor(l1, off, 64);
    }
    if (lane == 0) {
        l0 += db[0];
        l1 += db[1];
        const float m  = fmaxf(l0, l1);
        const float e0 = expf(l0 - m), e1 = expf(l1 - m);
        const float is = 1.f / (e0 + e1);
        out[b * 2 + 0] = e0 * is;
        out[b * 2 + 1] = e1 * is;
    }
}

extern "C" void kernel_launch(void* const* d_in, const int* in_sizes, int n_in,
                              void* d_out, int out_size, void* d_ws, size_t ws_size,
                              hipStream_t stream) {
    const float* X   = (const float*)d_in[0];  // bag_encoding [N,E]
    const float* Vwf = (const float*)d_in[1];  // [H,E]
    const float* Vb  = (const float*)d_in[2];  // [H]
    const float* ww  = (const float*)d_in[3];  // [1,H]
    const float* wb  = (const float*)d_in[4];  // [1]
    const float* dw  = (const float*)d_in[5];  // [2,E]
    const float* db  = (const float*)d_in[6];  // [2]
    const int*  bidx = (const int*)d_in[7];    // [N]
    float* out = (float*)d_out;

    // workspace layout: [Vw bf16: 256 KB][bag_acc: 1 MB][sum_alphas: 2 KB]
    __hip_bfloat16* Vwb = (__hip_bfloat16*)d_ws;
    float* bag_acc    = (float*)((char*)d_ws + (size_t)H_DIM * E_DIM * 2);
    float* sum_alphas = bag_acc + (size_t)NBAGS * E_DIM;

    hipMemsetAsync(bag_acc, 0, ((size_t)NBAGS * E_DIM + NBAGS) * sizeof(float), stream);
    vw_to_bf16<<<H_DIM * E_DIM / 1024, 256, 0, stream>>>(Vwf, Vwb);
    attn_main<<<N_INST / MI, 256, 0, stream>>>(X, Vwb, Vb, ww, wb, bidx,
                                               bag_acc, sum_alphas);
    finalize<<<NBAGS, 64, 0, stream>>>(bag_acc, sum_alphas, dw, db, out);
}

// Round 3
// 759.868 us; speedup vs baseline: 1.1370x; 1.1319x over previous
//
#include <hip/hip_runtime.h>
#include <hip/hip_bf16.h>

// Problem constants (fixed by the reference)
#define N_INST 262144
#define E_DIM  512
#define H_DIM  256
#define NBAGS  512
#define MI     32           // instances per tile
#define XS_STRIDE 520       // bf16 elems per LDS row (+8 pad breaks bank aliasing)
#define NBLOCKS 256         // persistent: 1 block per CU
#define TILES_PER_BLK (N_INST / MI / NBLOCKS)   // 32

typedef __bf16 bf16x8 __attribute__((ext_vector_type(8)));
typedef float  f32x4  __attribute__((ext_vector_type(4)));

__device__ __forceinline__ float fast_tanh(float x) {
    // tanh(x) = 1 - 2/(1+e^{2x}); amdgcn rcp ~1ulp, exp via v_exp_f32.
    float e = __expf(2.0f * x);
    return 1.0f - 2.0f * __builtin_amdgcn_rcpf(e + 1.0f);
}

// ---- prep: convert Vw fp32 -> bf16 (256x512)
__global__ void vw_to_bf16(const float* __restrict__ src,
                           __hip_bfloat16* __restrict__ dst) {
    int i = (blockIdx.x * 256 + threadIdx.x) * 4;
    float4 f = *(const float4*)(src + i);
    dst[i + 0] = __float2bfloat16(f.x);
    dst[i + 1] = __float2bfloat16(f.y);
    dst[i + 2] = __float2bfloat16(f.z);
    dst[i + 3] = __float2bfloat16(f.w);
}

// ---- persistent fused kernel. 8 waves; wave w owns H-cols [w*32, w*32+32).
// Vw B-fragments live in 128 VGPRs per lane for the whole kernel.
__global__ __launch_bounds__(512, 2) void attn_persist(
    const float* __restrict__ X,             // [N, E] fp32
    const __hip_bfloat16* __restrict__ Vw,   // [H, E] bf16
    const float* __restrict__ Vb,            // [H]
    const float* __restrict__ ww,            // [H]
    const float* __restrict__ wb,            // [1]
    const int* __restrict__ bidx,            // [N] sorted
    float* __restrict__ bag_acc,             // [NBAGS, E] fp32 (zeroed)
    float* __restrict__ sum_alphas)          // [NBAGS] fp32 (zeroed)
{
    __shared__ __hip_bfloat16 xs[2][MI][XS_STRIDE];  // 66560 B
    __shared__ float s_part[8][MI];
    __shared__ float a_sh[MI];
    __shared__ int   bag_sh[2][MI];

    const int tid  = threadIdx.x;
    const int wave = tid >> 6;      // 0..7
    const int lane = tid & 63;
    const int l16  = lane & 15;
    const int kgrp = lane >> 4;     // 0..3

    const int tile0 = blockIdx.x * TILES_PER_BLK;   // contiguous instance range

    // ---- load B-operand (this wave's 32 cols x all K) into registers, once
    bf16x8 breg[16][2];
    float ww_r[2], vb_r[2];
    {
        const __bf16* Vwp = (const __bf16*)Vw;
        #pragma unroll
        for (int nt = 0; nt < 2; nt++) {
            const int h = wave * 32 + nt * 16 + l16;
            ww_r[nt] = ww[h];
            vb_r[nt] = Vb[h];
            #pragma unroll
            for (int k = 0; k < 16; k++)
                breg[k][nt] = *(const bf16x8*)(Vwp + (size_t)h * E_DIM + k * 32 + kgrp * 8);
        }
    }

    // ---- stage-1 addressing: 512 threads, 8 float4/thread per tile
    const int c4 = tid & 127;       // float4 column 0..127
    const int r0 = tid >> 7;        // 0..3

    // prologue: stage tile 0 into xs[0]
    {
        const size_t i0 = (size_t)tile0 * MI;
        #pragma unroll
        for (int rr = 0; rr < 8; rr++) {
            const int r = rr * 4 + r0;
            float4 f = *(const float4*)(X + (i0 + r) * E_DIM + c4 * 4);
            __hip_bfloat16* dst = &xs[0][r][c4 * 4];
            dst[0] = __float2bfloat16(f.x);
            dst[1] = __float2bfloat16(f.y);
            dst[2] = __float2bfloat16(f.z);
            dst[3] = __float2bfloat16(f.w);
        }
        if (tid < MI) bag_sh[0][tid] = bidx[i0 + tid];
    }
    __syncthreads();

    // running per-bag accumulators (bags span tiles; bidx sorted)
    int   cur_bag = -1;
    float col_acc = 0.f;    // this thread's column (e = tid)
    float asum    = 0.f;

    int p = 0;
    for (int it = 0; it < TILES_PER_BLK; it++) {
        const size_t inst0 = (size_t)(tile0 + it) * MI;
        const bool has_next = (it + 1 < TILES_PER_BLK);

        // (1) issue next tile's global loads
        float4 ld[8];
        if (has_next) {
            const size_t i1 = inst0 + MI;
            #pragma unroll
            for (int rr = 0; rr < 8; rr++)
                ld[rr] = *(const float4*)(X + (i1 + rr * 4 + r0) * E_DIM + c4 * 4);
        }

        // (2) GEMM on xs[p] — pure LDS + register B
        f32x4 acc[2][2];
        #pragma unroll
        for (int mt = 0; mt < 2; mt++)
            #pragma unroll
            for (int nt = 0; nt < 2; nt++)
                acc[mt][nt] = (f32x4){0.f, 0.f, 0.f, 0.f};

        #pragma unroll
        for (int k = 0; k < 16; k++) {
            bf16x8 a_frag[2];
            #pragma unroll
            for (int mt = 0; mt < 2; mt++)
                a_frag[mt] = *(const bf16x8*)&xs[p][mt * 16 + l16][k * 32 + kgrp * 8];
            #pragma unroll
            for (int mt = 0; mt < 2; mt++)
                #pragma unroll
                for (int nt = 0; nt < 2; nt++)
                    acc[mt][nt] = __builtin_amdgcn_mfma_f32_16x16x32_bf16(
                        a_frag[mt], breg[k][nt], acc[mt][nt], 0, 0, 0);
        }

        // (3) drain next-tile loads -> bf16 -> xs[p^1] (hides HBM latency behind GEMM)
        if (has_next) {
            #pragma unroll
            for (int rr = 0; rr < 8; rr++) {
                const int r = rr * 4 + r0;
                __hip_bfloat16* dst = &xs[p ^ 1][r][c4 * 4];
                dst[0] = __float2bfloat16(ld[rr].x);
                dst[1] = __float2bfloat16(ld[rr].y);
                dst[2] = __float2bfloat16(ld[rr].z);
                dst[3] = __float2bfloat16(ld[rr].w);
            }
            if (tid < MI) bag_sh[p ^ 1][tid] = bidx[inst0 + MI + tid];
        }

        // (4) epilogue: v = tanh(acc+Vb); partial score = sum_h ww[h]*v
        #pragma unroll
        for (int mt = 0; mt < 2; mt++) {
            #pragma unroll
            for (int r = 0; r < 4; r++) {
                float t = 0.f;
                #pragma unroll
                for (int nt = 0; nt < 2; nt++)
                    t += ww_r[nt] * fast_tanh(acc[mt][nt][r] + vb_r[nt]);
                #pragma unroll
                for (int off = 1; off < 16; off <<= 1)
                    t += __shfl_xor(t, off, 64);
                if (l16 == 0)
                    s_part[wave][mt * 16 + kgrp * 4 + r] = t;
            }
        }
        __syncthreads();   // B1: s_part ready

        if (tid < MI) {
            float s = wb[0];
            #pragma unroll
            for (int w = 0; w < 8; w++) s += s_part[w][tid];
            a_sh[tid] = __expf(s);
        }
        __syncthreads();   // B2: a_sh ready

        // (5) segmented weighted accumulation; e = tid (one column/thread)
        for (int i = 0; i < MI; i++) {
            const int b = bag_sh[p][i];
            if (b != cur_bag) {
                if (cur_bag >= 0) {
                    atomicAdd(&bag_acc[(size_t)cur_bag * E_DIM + tid], col_acc);
                    if (tid == 0) atomicAdd(&sum_alphas[cur_bag], asum);
                }
                cur_bag = b; col_acc = 0.f; asum = 0.f;
            }
            const float a = a_sh[i];
            col_acc += a * __bfloat162float(xs[p][i][tid]);
            asum    += a;
        }
        __syncthreads();   // B3: xs[p^1]/bag_sh[p^1] complete; xs[p] free
        p ^= 1;
    }

    // final flush
    if (cur_bag >= 0) {
        atomicAdd(&bag_acc[(size_t)cur_bag * E_DIM + tid], col_acc);
        if (tid == 0) atomicAdd(&sum_alphas[cur_bag], asum);
    }
}

// ---- finalize: bag_sum = acc/sum, logits = bag_sum . dw^T + db, softmax
__global__ void finalize(const float* __restrict__ bag_acc,
                         const float* __restrict__ sum_alphas,
                         const float* __restrict__ dw,
                         const float* __restrict__ db,
                         float* __restrict__ out) {
    const int b = blockIdx.x;
    const int lane = threadIdx.x;
    const float sa = sum_alphas[b];
    const float inv = (sa > 0.f) ? (1.f / sa) : 0.f;   // empty bag -> bag_sum 0
    float l0 = 0.f, l1 = 0.f;
    for (int e = lane; e < E_DIM; e += 64) {
        const float bs = bag_acc[(size_t)b * E_DIM + e] * inv;
        l0 += bs * dw[e];
        l1 += bs * dw[E_DIM + e];
    }
    for (int off = 32; off; off >>= 1) {
        l0 += __shfl_xor(l0, off, 64);
        l1 += __shfl_xor(l1, off, 64);
    }
    if (lane == 0) {
        l0 += db[0];
        l1 += db[1];
        const float m  = fmaxf(l0, l1);
        const float e0 = expf(l0 - m), e1 = expf(l1 - m);
        const float is = 1.f / (e0 + e1);
        out[b * 2 + 0] = e0 * is;
        out[b * 2 + 1] = e1 * is;
    }
}

extern "C" void kernel_launch(void* const* d_in, const int* in_sizes, int n_in,
                              void* d_out, int out_size, void* d_ws, size_t ws_size,
                              hipStream_t stream) {
    const float* X   = (const float*)d_in[0];  // bag_encoding [N,E]
    const float* Vwf = (const float*)d_in[1];  // [H,E]
    const float* Vb  = (const float*)d_in[2];  // [H]
    const float* ww  = (const float*)d_in[3];  // [1,H]
    const float* wb  = (const float*)d_in[4];  // [1]
    const float* dw  = (const float*)d_in[5];  // [2,E]
    const float* db  = (const float*)d_in[6];  // [2]
    const int*  bidx = (const int*)d_in[7];    // [N]
    float* out = (float*)d_out;

    // workspace layout: [Vw bf16: 256 KB][bag_acc: 1 MB][sum_alphas: 2 KB]
    __hip_bfloat16* Vwb = (__hip_bfloat16*)d_ws;
    float* bag_acc    = (float*)((char*)d_ws + (size_t)H_DIM * E_DIM * 2);
    float* sum_alphas = bag_acc + (size_t)NBAGS * E_DIM;

    hipMemsetAsync(bag_acc, 0, ((size_t)NBAGS * E_DIM + NBAGS) * sizeof(float), stream);
    vw_to_bf16<<<H_DIM * E_DIM / 1024, 256, 0, stream>>>(Vwf, Vwb);
    attn_persist<<<NBLOCKS, 512, 0, stream>>>(X, Vwb, Vb, ww, wb, bidx,
                                              bag_acc, sum_alphas);
    finalize<<<NBAGS, 64, 0, stream>>>(bag_acc, sum_alphas, dw, db, out);
}